// Round 11
// baseline (51.670 us; speedup 1.0000x reference)
//
#include <hip/hip_runtime.h>
#include <math.h>

#define NN    8192
#define NPHI  32
#define ROWS  4
#define TPB   256     // 4 waves of 64
#define W     512     // tile width (cols)
#define TILES (NN / W)

// Two layouts of the y-table:
//   linear[j] = (y0,y1,y2,sq_j)
//   perm[...] = permuted for the pair-per-lane pattern: lane l, t in {0,1}
//               reads cols qb+2l+t of quarter qb via perm[qb + 64t + l]:
//               perm[(j & ~127) + 64*(j&1) + ((j&127)>>1)] = linear[j]
__global__ void prep_kernel(const float* __restrict__ nodes,
                            const float* __restrict__ W_theta,
                            float4* __restrict__ linear,
                            float4* __restrict__ perm) {
    int j = blockIdx.x * blockDim.x + threadIdx.x;
    if (j >= NN) return;
    float w0 = W_theta[0], w1 = W_theta[1], w2 = W_theta[2];
    float y0 = nodes[3 * j + 0] * w0;
    float y1 = nodes[3 * j + 1] * w1;
    float y2 = nodes[3 * j + 2] * w2;
    float sq = y0 * y0 + y1 * y1 + y2 * y2;
    float4 v = make_float4(y0, y1, y2, sq);
    linear[j] = v;
    perm[(j & ~127) + 64 * (j & 1) + ((j & 127) >> 1)] = v;
}

// DMA-STAGED VARIANT: adjacency is staged global->LDS via
// __builtin_amdgcn_global_load_lds (no result VGPRs -> load issue decoupled
// from consumption; outstanding misses not bound to wave waitcnt progress).
// 2048 blocks (8/CU), 4 rows/block, 512-col tiles double-buffered (16 KB LDS).
// Wave w stages row w; all waves compute all 4 rows over their col-quarter.
__launch_bounds__(TPB, 8)
__global__ void maxdist_kernel(const float* __restrict__ prev,
                               const int* __restrict__ adj,
                               const float* __restrict__ W_phi,
                               const float4* __restrict__ linear,
                               const float4* __restrict__ perm,
                               float* __restrict__ out) {
    const int tid  = threadIdx.x;
    const int lane = tid & 63;
    const int wave = tid >> 6;
    const int i0   = blockIdx.x * ROWS;

    __shared__ int   ladj[2][ROWS * W];   // 2 x 8 KB
    __shared__ float red[4][ROWS];

    float a[ROWS], b[ROWS], c[ROWS], m[ROWS];
#pragma unroll
    for (int r = 0; r < ROWS; ++r) {
        float4 p = linear[i0 + r];
        a[r] = -2.0f * p.x;
        b[r] = -2.0f * p.y;
        c[r] = -2.0f * p.z;
        m[r] = -INFINITY;   // running max of (sq_j - 2*dot); s_i added at the end
    }

    // stage one 512-col tile: wave w DMAs its row (2 KB) in two 1 KB calls.
    // LDS dest is wave-uniform; HW writes lane l at dest + 16*l bytes.
    const int* rowbase = adj + (size_t)(i0 + wave) * NN;
    auto stage = [&](int buf, int tile) {
#pragma unroll
        for (int h = 0; h < 2; ++h) {
            const int* src = rowbase + tile * W + h * 256 + lane * 4;
            int* dst = &ladj[buf][wave * W + h * 256];
            __builtin_amdgcn_global_load_lds(
                (const __attribute__((address_space(1))) int*)src,
                (__attribute__((address_space(3))) int*)dst, 16, 0, 0);
        }
    };

    stage(0, 0);
    __syncthreads();                       // implicit vmcnt(0): tile 0 resident

    for (int t = 0; t < TILES; ++t) {
        const int buf = t & 1;
        if (t + 1 < TILES) stage(buf ^ 1, t + 1);   // prefetch next tile
        __syncthreads();                   // drain: tiles t and t+1 resident

        // compute tile t: this wave's column quarter, all 4 rows
        const int qb = t * W + wave * 128;           // global col base
        const int lq = wave * 128 + 2 * lane;        // LDS col offset (pair)

        float4 p0 = perm[qb + lane];                 // y for col qb+2l
        float4 p1 = perm[qb + 64 + lane];            // y for col qb+2l+1

#pragma unroll
        for (int r = 0; r < ROWS; ++r) {
            const int2 ad = *(const int2*)&ladj[buf][r * W + lq];
            float d20 = fmaf(a[r], p0.x, fmaf(b[r], p0.y, fmaf(c[r], p0.z, p0.w)));
            float d21 = fmaf(a[r], p1.x, fmaf(b[r], p1.y, fmaf(c[r], p1.z, p1.w)));
            d20 = (ad.x > 0) ? d20 : -INFINITY;
            d21 = (ad.y > 0) ? d21 : -INFINITY;
            m[r] = fmaxf(m[r], fmaxf(d20, d21));
        }

        __syncthreads();                   // protect buf from next prefetch
    }

    // wave-level max reduce (each wave holds partials for all 4 rows over its quarter)
#pragma unroll
    for (int r = 0; r < ROWS; ++r) {
        float v = m[r];
#pragma unroll
        for (int off = 32; off > 0; off >>= 1)
            v = fmaxf(v, __shfl_xor(v, off, 64));
        m[r] = v;
    }

    if (lane == 0) {
#pragma unroll
        for (int r = 0; r < ROWS; ++r) red[wave][r] = m[r];
    }

    float wp = (lane < NPHI) ? W_phi[lane] : 0.0f;
#pragma unroll
    for (int off = 32; off > 0; off >>= 1) wp += __shfl_xor(wp, off, 64);
    const float wmean = wp / (float)NPHI;

    __syncthreads();

    if (tid < ROWS) {
        const int r = tid;
        const float d2max = fmaxf(fmaxf(red[0][r], red[1][r]),
                                  fmaxf(red[2][r], red[3][r]));
        const int i = i0 + r;
        const float si = linear[i].w;
        float d2 = si + d2max;             // -inf if no neighbor
        d2 = fmaxf(d2, 0.0f);
        const float md = sqrtf(d2);
        out[i] = (prev[i] + md * wmean) * 0.5f;
    }
}

extern "C" void kernel_launch(void* const* d_in, const int* in_sizes, int n_in,
                              void* d_out, int out_size, void* d_ws, size_t ws_size,
                              hipStream_t stream) {
    const float* prev    = (const float*)d_in[0];
    const float* nodes   = (const float*)d_in[1];
    const int*   adj     = (const int*)d_in[2];
    const float* W_phi   = (const float*)d_in[3];
    const float* W_theta = (const float*)d_in[4];
    float* out = (float*)d_out;

    float4* linear = (float4*)d_ws;
    float4* perm   = (float4*)d_ws + NN;

    prep_kernel<<<(NN + TPB - 1) / TPB, TPB, 0, stream>>>(nodes, W_theta, linear, perm);

    maxdist_kernel<<<NN / ROWS, TPB, 0, stream>>>(prev, adj, W_phi, linear, perm, out);
}

// Round 12
// 45.591 us; speedup vs baseline: 1.1333x; 1.1333x over previous
//
#include <hip/hip_runtime.h>
#include <math.h>

#define NN   8192
#define NPHI 32
#define ROWS 2
#define TPB  256   // 4 waves of 64

typedef int iv4 __attribute__((ext_vector_type(4)));

// SINGLE FUSED KERNEL (no prep, no ws): each lane owns 4 consecutive j's, so
// its y-inputs nodes[3*4l .. 3*4l+11] are one contiguous aligned 48 B run ->
// 3 float4 L2-hit loads, computed on the fly (~3 extra VALU ops/pair, amortized
// over ROWS=2). Saves the prep kernel + graph-node gap.
// Pipeline identical to R10: 2 chunks deep, 8 int4 adjacency loads in flight
// per wave, 32 waves/CU (lb 256,8), 4096 blocks = 16/CU.
__launch_bounds__(TPB, 8)
__global__ void maxdist_kernel(const float* __restrict__ prev,
                               const float* __restrict__ nodes,
                               const int* __restrict__ adj,
                               const float* __restrict__ W_phi,
                               const float* __restrict__ W_theta,
                               float* __restrict__ out) {
    const int tid  = threadIdx.x;
    const int lane = tid & 63;
    const int wave = tid >> 6;
    const int i0   = blockIdx.x * ROWS;

    const float w0 = W_theta[0], w1 = W_theta[1], w2 = W_theta[2];

    // per-row constants from nodes directly: a = -2*y_i
    float a[ROWS], b[ROWS], c[ROWS], m[ROWS];
#pragma unroll
    for (int r = 0; r < ROWS; ++r) {
        const float yi0 = nodes[3 * (i0 + r) + 0] * w0;
        const float yi1 = nodes[3 * (i0 + r) + 1] * w1;
        const float yi2 = nodes[3 * (i0 + r) + 2] * w2;
        a[r] = -2.0f * yi0;
        b[r] = -2.0f * yi1;
        c[r] = -2.0f * yi2;
        m[r] = -INFINITY;   // running max of (sq_j - 2*dot); s_i added at the end
    }

    const int woff = wave * 256 + lane * 4;   // lane's j-offset inside a 1KB chunk

    // consume one chunk: y computed on the fly from 12 contiguous floats
    auto consume = [&](const iv4* av, int jbase) {
        const float4* nb = (const float4*)(nodes + 3 * jbase);
        const float4 q0 = nb[0], q1 = nb[1], q2 = nb[2];
        const float nf[12] = {q0.x, q0.y, q0.z, q0.w,
                              q1.x, q1.y, q1.z, q1.w,
                              q2.x, q2.y, q2.z, q2.w};
#pragma unroll
        for (int t = 0; t < 4; ++t) {
            const float y0 = nf[3 * t + 0] * w0;
            const float y1 = nf[3 * t + 1] * w1;
            const float y2 = nf[3 * t + 2] * w2;
            const float sq = fmaf(y0, y0, fmaf(y1, y1, y2 * y2));
#pragma unroll
            for (int r = 0; r < ROWS; ++r) {
                float d2 = fmaf(a[r], y0, fmaf(b[r], y1, fmaf(c[r], y2, sq)));
                d2 = (av[r][t] > 0) ? d2 : -INFINITY;
                m[r] = fmaxf(m[r], d2);
            }
        }
    };

    // two 1KB chunks per iteration; all 8 adjacency loads issued up front
    for (int k = 0; k < NN / 1024; k += 2) {
        const int j00 = k * 1024 + woff;
        const int j01 = j00 + 1024;

        iv4 av0[ROWS], av1[ROWS];
#pragma unroll
        for (int r = 0; r < ROWS; ++r)
            av0[r] = *(const iv4*)(adj + (size_t)(i0 + r) * NN + j00);
#pragma unroll
        for (int r = 0; r < ROWS; ++r)
            av1[r] = *(const iv4*)(adj + (size_t)(i0 + r) * NN + j01);

        consume(av0, j00);
        consume(av1, j01);
    }

    // wave-level max reduce
#pragma unroll
    for (int r = 0; r < ROWS; ++r) {
        float v = m[r];
#pragma unroll
        for (int off = 32; off > 0; off >>= 1)
            v = fmaxf(v, __shfl_xor(v, off, 64));
        m[r] = v;
    }

    __shared__ float red[4][ROWS];
    if (lane == 0) {
#pragma unroll
        for (int r = 0; r < ROWS; ++r) red[wave][r] = m[r];
    }

    float wp = (lane < NPHI) ? W_phi[lane] : 0.0f;
#pragma unroll
    for (int off = 32; off > 0; off >>= 1) wp += __shfl_xor(wp, off, 64);
    const float wmean = wp / (float)NPHI;

    __syncthreads();

    if (tid < ROWS) {
        const int r = tid;
        const float d2max = fmaxf(fmaxf(red[0][r], red[1][r]),
                                  fmaxf(red[2][r], red[3][r]));
        const int i = i0 + r;
        const float yi0 = nodes[3 * i + 0] * w0;
        const float yi1 = nodes[3 * i + 1] * w1;
        const float yi2 = nodes[3 * i + 2] * w2;
        const float si  = fmaf(yi0, yi0, fmaf(yi1, yi1, yi2 * yi2));
        float d2 = si + d2max;           // -inf if no neighbor
        d2 = fmaxf(d2, 0.0f);
        const float md = sqrtf(d2);
        out[i] = (prev[i] + md * wmean) * 0.5f;
    }
}

extern "C" void kernel_launch(void* const* d_in, const int* in_sizes, int n_in,
                              void* d_out, int out_size, void* d_ws, size_t ws_size,
                              hipStream_t stream) {
    const float* prev    = (const float*)d_in[0];
    const float* nodes   = (const float*)d_in[1];
    const int*   adj     = (const int*)d_in[2];
    const float* W_phi   = (const float*)d_in[3];
    const float* W_theta = (const float*)d_in[4];
    float* out = (float*)d_out;

    maxdist_kernel<<<NN / ROWS, TPB, 0, stream>>>(prev, nodes, adj, W_phi, W_theta, out);
}